// Round 17
// baseline (1928.302 us; speedup 1.0000x reference)
//
#pragma clang fp contract(off)
#include <hip/hip_runtime.h>
#include <math.h>

// MotionTrackingLK — PASSING numerics (R12 config), optimized execution v5.
// Numerics contract (frozen, bitwise): f32 everywhere, contract off,
// single-op statements; einsums = ascending-k scalar single-accumulator
// chains; Sobel = npyv SSE3 9-run; bilinear left-to-right; per-point f32
// sampler carry. Perf v5 (bitwise-neutral): ODD LDS row strides (25) for
// the Sobel window and the staged region — gcd(25,32)=1 spreads gather
// banks (v4's stride-24 had gcd 8 -> 4-8-way conflicts, 4.6e7 cycles).

#define WINSZ 21
#define KPTS  441
#define NPT   7      // points per lane: lanes 0..62 own 7 consecutive k
#define PSTR  452    // pqT row stride (452%32==4, 16B-aligned rows)
#define RDIM  24     // staged region is 24x24 pixels
#define RSTR  25     // region LDS row stride (odd -> conflict-free gathers)
#define RPX   576    // 24*24 = 9*64 staged pixels

struct SB {
  float fw[23][25];      // first window + zero ring; stride 25 (odd)
  float pqT[6][PSTR];    // rows 0-3: ATA products; rows 4-5: ATb products
  float regA[RDIM * RSTR];  // staged F0 region (24 rows x stride 25)
  float regB[RDIM * RSTR];  // staged F1 region
};

// ---- slow path (original, bit-identical gather from global) ----
__device__ __forceinline__ float bilinf(const float* __restrict__ F,
                                        float x, float y) {
  #pragma clang fp contract(off)
  float fx = floorf(x), fy = floorf(y);
  float x0 = fminf(fmaxf(fx, 0.0f), 511.0f);
  float x1a = fx + 1.0f;
  float x1 = fminf(fmaxf(x1a, 0.0f), 511.0f);
  float y0 = fminf(fmaxf(fy, 0.0f), 511.0f);
  float y1a = fy + 1.0f;
  float y1 = fminf(fmaxf(y1a, 0.0f), 511.0f);
  float dy1 = y1 - y, dx1 = x1 - x, dy0 = y - y0, dx0 = x - x0;
  float wa = dy1 * dx1;
  float wb = dy1 * dx0;
  float wc = dy0 * dx1;
  float wd = dy0 * dx0;
  int jx0 = (int)x0, jx1 = (int)x1, jy0 = (int)y0, jy1 = (int)y1;
  float Ia = F[jy0 * 512 + jx0];
  float Ib = F[jy0 * 512 + jx1];
  float Ic = F[jy1 * 512 + jx0];
  float Id = F[jy1 * 512 + jx1];
  float pA = wa * Ia;
  float pB = wb * Ib;
  float pC = wc * Ic;
  float pD = wd * Id;
  float s = pA + pB;
  s = s + pC;
  s = s + pD;
  return s;
}

// ---- fast path: weights (interior => clips are identities, bit-exact) ----
__device__ __forceinline__ void wcalc(float x, float y, int cb,
                                      float* w, int* idx) {
  #pragma clang fp contract(off)
  float fx = floorf(x), fy = floorf(y);
  float x1 = fx + 1.0f;          // == clip(fx+1) when interior
  float y1 = fy + 1.0f;
  float dy1 = y1 - y, dx1 = x1 - x, dy0 = y - fy, dx0 = x - fx;
  w[0] = dy1 * dx1;
  w[1] = dy1 * dx0;
  w[2] = dy0 * dx1;
  w[3] = dy0 * dx0;
  int ix0 = (int)fx, iy0 = (int)fy;
  *idx = iy0 * RSTR + ix0 - cb;  // region-relative tap index (stride 25)
}

__device__ __forceinline__ float rsum(const float* __restrict__ reg,
                                      const float* w, int idx) {
  #pragma clang fp contract(off)
  float Ia = reg[idx];
  float Ib = reg[idx + 1];
  float Ic = reg[idx + RSTR];
  float Id = reg[idx + RSTR + 1];
  float pA = w[0] * Ia;
  float pB = w[1] * Ib;
  float pC = w[2] * Ic;
  float pD = w[3] * Id;
  float s = pA + pB;
  s = s + pC;
  s = s + pD;
  return s;
}

__global__ __launch_bounds__(64) void lk_track(
    const float* __restrict__ track_locs,  // (B, NT, 2)
    const float* __restrict__ imgs,        // (B, S, 512, 512, 1)
    float* __restrict__ out)               // (B, NT, S, 2)
{
  #pragma clang fp contract(off)
  __shared__ SB S;
  const float CRF = (float)(512.0 / 21.0);  // np.float32(W/WIN)
  const int SS = 16, HW = 512 * 512;

  const int tr   = blockIdx.x;   // b*256 + n
  const int b    = tr >> 8;
  const int lane = threadIdx.x;

  for (int i = lane; i < 23 * 25; i += 64) (&S.fw[0][0])[i] = 0.0f;

  const bool act = (lane < 63);
  int   rr[NPT], cc[NPT];
  float gxv[NPT], gyv[NPT], wwv[NPT];
  const double gnorm = 1.0 / (2.0 * sqrt(2.0 * 3.141592653589793));
#pragma unroll
  for (int j = 0; j < NPT; j++) {
    int k = lane * NPT + j;
    if (k >= KPTS) k = 0;                  // lane 63: dummy (never stored)
    int r = k / WINSZ, c = k % WINSZ;
    rr[j] = r; cc[j] = c;
    gxv[j] = (c == 20) ? 1.0f : (float)((double)c * 0.1 - 1.0);
    gyv[j] = (r == 20) ? 1.0f : (float)((double)r * 0.1 - 1.0);
    double dd = sqrt((double)((c - 10) * (c - 10) + (r - 10) * (r - 10)));
    double q  = dd / 2.0;
    wwv[j] = (float)(gnorm * exp(-0.5 * (q * q)));
  }

  // staging offsets: region pixel f = lane + 64*i -> (r,c) = (f/24, f%24)
  int soff[9], loff[9];
#pragma unroll
  for (int i = 0; i < 9; i++) {
    int f = lane + 64 * i;
    int r = f / RDIM;
    int c = f - RDIM * r;
    soff[i] = r * 512 + c;      // global offset
    loff[i] = r * RSTR + c;     // LDS offset (stride 25)
  }

  // init = tl*cr + cr, f32 mul then f32 add, no FMA
  const float* tl = track_locs + (size_t)tr * 2;
  float mx = tl[0] * CRF; float initx = mx + CRF;
  float my = tl[1] * CRF; float inity = my + CRF;

  float sx[NPT], sy[NPT];
#pragma unroll
  for (int j = 0; j < NPT; j++) { sx[j] = initx + gxv[j]; sy[j] = inity + gyv[j]; }

  float px = initx, py = inity;            // pos carry (f32)
  if (lane == 0) {
    float* o = out + (size_t)tr * SS * 2;
    float n0 = initx - CRF; o[0] = n0 / CRF;
    float n1 = inity - CRF; o[1] = n1 / CRF;
  }

  int g6 = lane >> 3; if (g6 > 5) g6 = g6 - 2;   // lanes 48-63 shadow grps 4,5
  const int grp2 = lane >> 5;                    // 0..1: ATb component group
  const float* row6 = &S.pqT[g6][0];
  const float* rowB = &S.pqT[4 + grp2][0];

  float fv[NPT], scv[NPT], ixv[NPT], iyv[NPT];

  for (int t = 0; t < SS - 1; t++) {
    const float* F0 = imgs + ((size_t)b * SS + t) * HW;
    const float* F1 = F0 + HW;

    __syncthreads();                       // prev step's LDS reads done

    // ---- region bounds (uniform): min/max of sampler, scaled ----
    float xmn = sx[0], xmx = sx[0], ymn = sy[0], ymx = sy[0];
#pragma unroll
    for (int j = 1; j < NPT; j++) {
      xmn = fminf(xmn, sx[j]); xmx = fmaxf(xmx, sx[j]);
      ymn = fminf(ymn, sy[j]); ymx = fmaxf(ymx, sy[j]);
    }
#pragma unroll
    for (int m = 32; m >= 1; m >>= 1) {
      xmn = fminf(xmn, __shfl_xor(xmn, m, 64));
      xmx = fmaxf(xmx, __shfl_xor(xmx, m, 64));
      ymn = fminf(ymn, __shfl_xor(ymn, m, 64));
      ymx = fmaxf(ymx, __shfl_xor(ymx, m, 64));
    }
    float xminp = xmn * 10.5f, xmaxp = xmx * 10.5f;   // monotone => exact bounds
    float yminp = ymn * 10.5f, ymaxp = ymx * 10.5f;
    float bxf = floorf(xminp), byf = floorf(yminp);
    bool fast = (bxf >= 0.0f) && (byf >= 0.0f) &&
                (bxf <= 488.0f) && (byf <= 488.0f) &&
                (xmaxp < bxf + 23.0f) && (ymaxp < byf + 23.0f);
    int gbase = 0, cb = 0;
    if (fast) {
      int bx = (int)bxf, by = (int)byf;
      gbase = by * 512 + bx;
      cb = by * RSTR + bx;
    }

    if (fast) {
#pragma unroll
      for (int i = 0; i < 9; i++) S.regA[loff[i]] = F0[gbase + soff[i]];
#pragma unroll
      for (int i = 0; i < 9; i++) S.regB[loff[i]] = F1[gbase + soff[i]];
      __syncthreads();
#pragma unroll
      for (int j = 0; j < NPT; j++) {
        float x = sx[j] * 10.5f, y = sy[j] * 10.5f;
        float w[4]; int id;
        wcalc(x, y, cb, w, &id);           // shared weights for F0 & F1
        fv[j]  = rsum(S.regA, w, id);
        scv[j] = rsum(S.regB, w, id);
        if (act) S.fw[rr[j] + 1][cc[j] + 1] = fv[j];
      }
    } else {
#pragma unroll
      for (int j = 0; j < NPT; j++) {
        float x = sx[j] * 10.5f, y = sy[j] * 10.5f;
        fv[j]  = bilinf(F0, x, y);
        scv[j] = bilinf(F1, x, y);
        if (act) S.fw[rr[j] + 1][cc[j] + 1] = fv[j];
      }
    }
    __syncthreads();

    // Sobel (npyv SSE3 9-run order) + ATA products + it=0 ATb products,
    // computed by OWNING lane (bitwise identical values).
#pragma unroll
    for (int j = 0; j < NPT; j++) {
      int r = rr[j], c = cc[j];
      float a00 = S.fw[r][c],     a01 = S.fw[r][c + 1],     a02 = S.fw[r][c + 2];
      float a10 = S.fw[r + 1][c],                           a12 = S.fw[r + 1][c + 2];
      float a20 = S.fw[r + 2][c], a21 = S.fw[r + 2][c + 1], a22 = S.fw[r + 2][c + 2];
      float xc0 = -a00;
      float xc1 = 2.0f * a12;
      float xc2 = a02 + (-a20);
      float xc3 = -2.0f * a10;
      float xh0 = xc0 + xc1;
      float xh1 = xc2 + xc3;
      float Ix = xh0 + xh1;
      Ix = Ix + a22;
      float yc0 = -a00;
      float yc1 = -2.0f * a01;
      float yc2 = (-a02) + a20;
      float yc3 = 2.0f * a21;
      float yh0 = yc0 + yc1;
      float yh1 = yc2 + yc3;
      float Iy = yh0 + yh1;
      Iy = Iy + a22;
      ixv[j] = Ix; iyv[j] = Iy;
      if (act) {
        int k = lane * NPT + j;
        float tx = Ix * wwv[j];
        float ty = Iy * wwv[j];
        float p0 = Ix * tx;
        float p1 = Ix * ty;
        float p2 = Iy * tx;
        float p3 = Iy * ty;
        S.pqT[0][k] = p0;
        S.pqT[1][k] = p1;
        S.pqT[2][k] = p2;
        S.pqT[3][k] = p3;
        float d2 = fv[j] - scv[j];         // it=0 ATb products
        float bw = d2 * wwv[j];
        float u0 = ixv[j] * bw;
        float u1 = iyv[j] * bw;
        S.pqT[4][k] = u0;
        S.pqT[5][k] = u1;
      }
    }
    __syncthreads();

    // Step-start pass: ALL 6 chains (4 ATA + 2 ATb0) in 6x8-lane groups.
    float acc = 0.f;
#pragma unroll 11
    for (int m = 0; m < 110; m++) {
      float4 v = *reinterpret_cast<const float4*>(&row6[4 * m]);
      acc = acc + v.x;
      acc = acc + v.y;
      acc = acc + v.z;
      acc = acc + v.w;
    }
    acc = acc + row6[440];
    float aa = __shfl(acc, 0,  64);
    float bb = __shfl(acc, 8,  64);
    float cN = __shfl(acc, 16, 64);
    float dN = __shfl(acc, 24, 64);
    float s0 = __shfl(acc, 32, 64);
    float s1 = __shfl(acc, 40, 64);
    float q0 = aa * dN;
    float q1 = bb * cN;
    float det = q0 - q1;
    det = det + 1e-7f;
    float inv_det = 1.0f / det;

    float svx = 0.f, svy = 0.f;
    for (int it = 0; it < 5; it++) {
      if (it > 0) {
        float xmn2 = sx[0], xmx2 = sx[0], ymn2 = sy[0], ymx2 = sy[0];
#pragma unroll
        for (int j = 1; j < NPT; j++) {
          xmn2 = fminf(xmn2, sx[j]); xmx2 = fmaxf(xmx2, sx[j]);
          ymn2 = fminf(ymn2, sy[j]); ymx2 = fmaxf(ymx2, sy[j]);
        }
#pragma unroll
        for (int m = 32; m >= 1; m >>= 1) {
          xmn2 = fminf(xmn2, __shfl_xor(xmn2, m, 64));
          xmx2 = fmaxf(xmx2, __shfl_xor(xmx2, m, 64));
          ymn2 = fminf(ymn2, __shfl_xor(ymn2, m, 64));
          ymx2 = fmaxf(ymx2, __shfl_xor(ymx2, m, 64));
        }
        float xminp2 = xmn2 * 10.5f, xmaxp2 = xmx2 * 10.5f;
        float yminp2 = ymn2 * 10.5f, ymaxp2 = ymx2 * 10.5f;
        float bxf2 = floorf(xminp2), byf2 = floorf(yminp2);
        bool fast2 = (bxf2 >= 0.0f) && (byf2 >= 0.0f) &&
                     (bxf2 <= 488.0f) && (byf2 <= 488.0f) &&
                     (xmaxp2 < bxf2 + 23.0f) && (ymaxp2 < byf2 + 23.0f);
        if (fast2) {
          int bx2 = (int)bxf2, by2 = (int)byf2;
          int gbase2 = by2 * 512 + bx2;
          int cb2 = by2 * RSTR + bx2;
#pragma unroll
          for (int i = 0; i < 9; i++) S.regB[loff[i]] = F1[gbase2 + soff[i]];
          __syncthreads();
#pragma unroll
          for (int j = 0; j < NPT; j++) {
            float x = sx[j] * 10.5f, y = sy[j] * 10.5f;
            float w[4]; int id;
            wcalc(x, y, cb2, w, &id);
            scv[j] = rsum(S.regB, w, id);
          }
        } else {
#pragma unroll
          for (int j = 0; j < NPT; j++) {
            float x = sx[j] * 10.5f, y = sy[j] * 10.5f;
            scv[j] = bilinf(F1, x, y);
          }
        }
#pragma unroll
        for (int j = 0; j < NPT; j++) {
          if (act) {
            int k = lane * NPT + j;
            float d2 = fv[j] - scv[j];
            float bw = d2 * wwv[j];
            float u0 = ixv[j] * bw;
            float u1 = iyv[j] * bw;
            S.pqT[4][k] = u0;
            S.pqT[5][k] = u1;
          }
        }
        __syncthreads();
        // ATb: 2 chains in 2x32-lane groups, b128 reads, ascending-k adds.
        float accB = 0.f;
#pragma unroll 11
        for (int m = 0; m < 110; m++) {
          float4 v = *reinterpret_cast<const float4*>(&rowB[4 * m]);
          accB = accB + v.x;
          accB = accB + v.y;
          accB = accB + v.z;
          accB = accB + v.w;
        }
        accB = accB + rowB[440];
        s0 = __shfl(accB, 0,  64);
        s1 = __shfl(accB, 32, 64);
      }
      float e0 = dN * s0;
      float e1 = bb * s1;
      float numx = e0 - e1;
      float vx = inv_det * numx;
      float f0 = (-cN) * s0;
      float f1 = aa * s1;
      float numy = f0 + f1;
      float vy = inv_det * numy;
#pragma unroll
      for (int j = 0; j < NPT; j++) { sx[j] = sx[j] + vx; sy[j] = sy[j] + vy; }
      if (it == 0) { svx = vx;       svy = vy; }
      else         { svx = svx + vx; svy = svy + vy; }
      __syncthreads();                   // pqT/reg reads done before rewrite
    }

    px = px + svx; py = py + svy;        // pos = prev + sum_v (f32)
    if (lane == 0) {
      float* o = out + ((size_t)tr * SS + (t + 1)) * 2;
      float n0 = px - CRF; o[0] = n0 / CRF;
      float n1 = py - CRF; o[1] = n1 / CRF;
    }
  }
}

extern "C" void kernel_launch(void* const* d_in, const int* in_sizes, int n_in,
                              void* d_out, int out_size, void* d_ws, size_t ws_size,
                              hipStream_t stream) {
  const float* tl   = (const float*)d_in[0];  // (8,256,2) f32
  const float* imgs = (const float*)d_in[1];  // (8,16,512,512,1) f32
  float* o          = (float*)d_out;          // 65536 f32
  lk_track<<<dim3(2048), dim3(64), 0, stream>>>(tl, imgs, o);
}

// Round 18
// 333.992 us; speedup vs baseline: 5.7735x; 5.7735x over previous
//
#pragma clang fp contract(off)
#include <hip/hip_runtime.h>
#include <math.h>

// MotionTrackingLK — PASSING numerics (R12 config), optimized execution v6.
// Numerics contract (frozen, bitwise): f32 everywhere, contract off,
// single-op statements; einsums = ascending-k scalar single-accumulator
// chains; Sobel = npyv SSE3 9-run; bilinear left-to-right; per-point f32
// sampler carry.
// Perf v6: v5's odd strides (conflict fix) + pqT moved to struct offset 0
// so its rows stay 16B-aligned for ds_read_b128 (v5 put fw[23][25]=2300B
// first -> pqT rows at 12 mod 16 -> misaligned b128 slow path, 5x stall).

#define WINSZ 21
#define KPTS  441
#define NPT   7      // points per lane: lanes 0..62 own 7 consecutive k
#define PSTR  452    // pqT row stride: 452*4=1808B, 16B-multiple; 452%32==4
#define RDIM  24     // staged region is 24x24 pixels
#define RSTR  25     // region LDS row stride (odd -> conflict-free gathers)

struct SB {
  float pqT[6][PSTR];       // offset 0: rows 16B-aligned for b128 chain reads
  float fw[23][25];         // Sobel window + zero ring; odd stride
  float regA[RDIM * RSTR];  // staged F0 region (24 rows x stride 25)
  float regB[RDIM * RSTR];  // staged F1 region
};

// ---- slow path (original, bit-identical gather from global) ----
__device__ __forceinline__ float bilinf(const float* __restrict__ F,
                                        float x, float y) {
  #pragma clang fp contract(off)
  float fx = floorf(x), fy = floorf(y);
  float x0 = fminf(fmaxf(fx, 0.0f), 511.0f);
  float x1a = fx + 1.0f;
  float x1 = fminf(fmaxf(x1a, 0.0f), 511.0f);
  float y0 = fminf(fmaxf(fy, 0.0f), 511.0f);
  float y1a = fy + 1.0f;
  float y1 = fminf(fmaxf(y1a, 0.0f), 511.0f);
  float dy1 = y1 - y, dx1 = x1 - x, dy0 = y - y0, dx0 = x - x0;
  float wa = dy1 * dx1;
  float wb = dy1 * dx0;
  float wc = dy0 * dx1;
  float wd = dy0 * dx0;
  int jx0 = (int)x0, jx1 = (int)x1, jy0 = (int)y0, jy1 = (int)y1;
  float Ia = F[jy0 * 512 + jx0];
  float Ib = F[jy0 * 512 + jx1];
  float Ic = F[jy1 * 512 + jx0];
  float Id = F[jy1 * 512 + jx1];
  float pA = wa * Ia;
  float pB = wb * Ib;
  float pC = wc * Ic;
  float pD = wd * Id;
  float s = pA + pB;
  s = s + pC;
  s = s + pD;
  return s;
}

// ---- fast path: weights (interior => clips are identities, bit-exact) ----
__device__ __forceinline__ void wcalc(float x, float y, int cb,
                                      float* w, int* idx) {
  #pragma clang fp contract(off)
  float fx = floorf(x), fy = floorf(y);
  float x1 = fx + 1.0f;          // == clip(fx+1) when interior
  float y1 = fy + 1.0f;
  float dy1 = y1 - y, dx1 = x1 - x, dy0 = y - fy, dx0 = x - fx;
  w[0] = dy1 * dx1;
  w[1] = dy1 * dx0;
  w[2] = dy0 * dx1;
  w[3] = dy0 * dx0;
  int ix0 = (int)fx, iy0 = (int)fy;
  *idx = iy0 * RSTR + ix0 - cb;  // region-relative tap index (stride 25)
}

__device__ __forceinline__ float rsum(const float* __restrict__ reg,
                                      const float* w, int idx) {
  #pragma clang fp contract(off)
  float Ia = reg[idx];
  float Ib = reg[idx + 1];
  float Ic = reg[idx + RSTR];
  float Id = reg[idx + RSTR + 1];
  float pA = w[0] * Ia;
  float pB = w[1] * Ib;
  float pC = w[2] * Ic;
  float pD = w[3] * Id;
  float s = pA + pB;
  s = s + pC;
  s = s + pD;
  return s;
}

__global__ __launch_bounds__(64) void lk_track(
    const float* __restrict__ track_locs,  // (B, NT, 2)
    const float* __restrict__ imgs,        // (B, S, 512, 512, 1)
    float* __restrict__ out)               // (B, NT, S, 2)
{
  #pragma clang fp contract(off)
  __shared__ SB S;
  const float CRF = (float)(512.0 / 21.0);  // np.float32(W/WIN)
  const int SS = 16, HW = 512 * 512;

  const int tr   = blockIdx.x;   // b*256 + n
  const int b    = tr >> 8;
  const int lane = threadIdx.x;

  for (int i = lane; i < 23 * 25; i += 64) (&S.fw[0][0])[i] = 0.0f;

  const bool act = (lane < 63);
  int   rr[NPT], cc[NPT];
  float gxv[NPT], gyv[NPT], wwv[NPT];
  const double gnorm = 1.0 / (2.0 * sqrt(2.0 * 3.141592653589793));
#pragma unroll
  for (int j = 0; j < NPT; j++) {
    int k = lane * NPT + j;
    if (k >= KPTS) k = 0;                  // lane 63: dummy (never stored)
    int r = k / WINSZ, c = k % WINSZ;
    rr[j] = r; cc[j] = c;
    gxv[j] = (c == 20) ? 1.0f : (float)((double)c * 0.1 - 1.0);
    gyv[j] = (r == 20) ? 1.0f : (float)((double)r * 0.1 - 1.0);
    double dd = sqrt((double)((c - 10) * (c - 10) + (r - 10) * (r - 10)));
    double q  = dd / 2.0;
    wwv[j] = (float)(gnorm * exp(-0.5 * (q * q)));
  }

  // staging offsets: region pixel f = lane + 64*i -> (r,c) = (f/24, f%24)
  int soff[9], loff[9];
#pragma unroll
  for (int i = 0; i < 9; i++) {
    int f = lane + 64 * i;
    int r = f / RDIM;
    int c = f - RDIM * r;
    soff[i] = r * 512 + c;      // global offset
    loff[i] = r * RSTR + c;     // LDS offset (stride 25)
  }

  // init = tl*cr + cr, f32 mul then f32 add, no FMA
  const float* tl = track_locs + (size_t)tr * 2;
  float mx = tl[0] * CRF; float initx = mx + CRF;
  float my = tl[1] * CRF; float inity = my + CRF;

  float sx[NPT], sy[NPT];
#pragma unroll
  for (int j = 0; j < NPT; j++) { sx[j] = initx + gxv[j]; sy[j] = inity + gyv[j]; }

  float px = initx, py = inity;            // pos carry (f32)
  if (lane == 0) {
    float* o = out + (size_t)tr * SS * 2;
    float n0 = initx - CRF; o[0] = n0 / CRF;
    float n1 = inity - CRF; o[1] = n1 / CRF;
  }

  int g6 = lane >> 3; if (g6 > 5) g6 = g6 - 2;   // lanes 48-63 shadow grps 4,5
  const int grp2 = lane >> 5;                    // 0..1: ATb component group
  const float* row6 = &S.pqT[g6][0];
  const float* rowB = &S.pqT[4 + grp2][0];

  float fv[NPT], scv[NPT], ixv[NPT], iyv[NPT];

  for (int t = 0; t < SS - 1; t++) {
    const float* F0 = imgs + ((size_t)b * SS + t) * HW;
    const float* F1 = F0 + HW;

    __syncthreads();                       // prev step's LDS reads done

    // ---- region bounds (uniform): min/max of sampler, scaled ----
    float xmn = sx[0], xmx = sx[0], ymn = sy[0], ymx = sy[0];
#pragma unroll
    for (int j = 1; j < NPT; j++) {
      xmn = fminf(xmn, sx[j]); xmx = fmaxf(xmx, sx[j]);
      ymn = fminf(ymn, sy[j]); ymx = fmaxf(ymx, sy[j]);
    }
#pragma unroll
    for (int m = 32; m >= 1; m >>= 1) {
      xmn = fminf(xmn, __shfl_xor(xmn, m, 64));
      xmx = fmaxf(xmx, __shfl_xor(xmx, m, 64));
      ymn = fminf(ymn, __shfl_xor(ymn, m, 64));
      ymx = fmaxf(ymx, __shfl_xor(ymx, m, 64));
    }
    float xminp = xmn * 10.5f, xmaxp = xmx * 10.5f;   // monotone => exact bounds
    float yminp = ymn * 10.5f, ymaxp = ymx * 10.5f;
    float bxf = floorf(xminp), byf = floorf(yminp);
    bool fast = (bxf >= 0.0f) && (byf >= 0.0f) &&
                (bxf <= 488.0f) && (byf <= 488.0f) &&
                (xmaxp < bxf + 23.0f) && (ymaxp < byf + 23.0f);
    int gbase = 0, cb = 0;
    if (fast) {
      int bx = (int)bxf, by = (int)byf;
      gbase = by * 512 + bx;
      cb = by * RSTR + bx;
    }

    if (fast) {
#pragma unroll
      for (int i = 0; i < 9; i++) S.regA[loff[i]] = F0[gbase + soff[i]];
#pragma unroll
      for (int i = 0; i < 9; i++) S.regB[loff[i]] = F1[gbase + soff[i]];
      __syncthreads();
#pragma unroll
      for (int j = 0; j < NPT; j++) {
        float x = sx[j] * 10.5f, y = sy[j] * 10.5f;
        float w[4]; int id;
        wcalc(x, y, cb, w, &id);           // shared weights for F0 & F1
        fv[j]  = rsum(S.regA, w, id);
        scv[j] = rsum(S.regB, w, id);
        if (act) S.fw[rr[j] + 1][cc[j] + 1] = fv[j];
      }
    } else {
#pragma unroll
      for (int j = 0; j < NPT; j++) {
        float x = sx[j] * 10.5f, y = sy[j] * 10.5f;
        fv[j]  = bilinf(F0, x, y);
        scv[j] = bilinf(F1, x, y);
        if (act) S.fw[rr[j] + 1][cc[j] + 1] = fv[j];
      }
    }
    __syncthreads();

    // Sobel (npyv SSE3 9-run order) + ATA products + it=0 ATb products,
    // computed by OWNING lane (bitwise identical values).
#pragma unroll
    for (int j = 0; j < NPT; j++) {
      int r = rr[j], c = cc[j];
      float a00 = S.fw[r][c],     a01 = S.fw[r][c + 1],     a02 = S.fw[r][c + 2];
      float a10 = S.fw[r + 1][c],                           a12 = S.fw[r + 1][c + 2];
      float a20 = S.fw[r + 2][c], a21 = S.fw[r + 2][c + 1], a22 = S.fw[r + 2][c + 2];
      float xc0 = -a00;
      float xc1 = 2.0f * a12;
      float xc2 = a02 + (-a20);
      float xc3 = -2.0f * a10;
      float xh0 = xc0 + xc1;
      float xh1 = xc2 + xc3;
      float Ix = xh0 + xh1;
      Ix = Ix + a22;
      float yc0 = -a00;
      float yc1 = -2.0f * a01;
      float yc2 = (-a02) + a20;
      float yc3 = 2.0f * a21;
      float yh0 = yc0 + yc1;
      float yh1 = yc2 + yc3;
      float Iy = yh0 + yh1;
      Iy = Iy + a22;
      ixv[j] = Ix; iyv[j] = Iy;
      if (act) {
        int k = lane * NPT + j;
        float tx = Ix * wwv[j];
        float ty = Iy * wwv[j];
        float p0 = Ix * tx;
        float p1 = Ix * ty;
        float p2 = Iy * tx;
        float p3 = Iy * ty;
        S.pqT[0][k] = p0;
        S.pqT[1][k] = p1;
        S.pqT[2][k] = p2;
        S.pqT[3][k] = p3;
        float d2 = fv[j] - scv[j];         // it=0 ATb products
        float bw = d2 * wwv[j];
        float u0 = ixv[j] * bw;
        float u1 = iyv[j] * bw;
        S.pqT[4][k] = u0;
        S.pqT[5][k] = u1;
      }
    }
    __syncthreads();

    // Step-start pass: ALL 6 chains (4 ATA + 2 ATb0) in 6x8-lane groups.
    float acc = 0.f;
#pragma unroll 11
    for (int m = 0; m < 110; m++) {
      float4 v = *reinterpret_cast<const float4*>(&row6[4 * m]);
      acc = acc + v.x;
      acc = acc + v.y;
      acc = acc + v.z;
      acc = acc + v.w;
    }
    acc = acc + row6[440];
    float aa = __shfl(acc, 0,  64);
    float bb = __shfl(acc, 8,  64);
    float cN = __shfl(acc, 16, 64);
    float dN = __shfl(acc, 24, 64);
    float s0 = __shfl(acc, 32, 64);
    float s1 = __shfl(acc, 40, 64);
    float q0 = aa * dN;
    float q1 = bb * cN;
    float det = q0 - q1;
    det = det + 1e-7f;
    float inv_det = 1.0f / det;

    float svx = 0.f, svy = 0.f;
    for (int it = 0; it < 5; it++) {
      if (it > 0) {
        float xmn2 = sx[0], xmx2 = sx[0], ymn2 = sy[0], ymx2 = sy[0];
#pragma unroll
        for (int j = 1; j < NPT; j++) {
          xmn2 = fminf(xmn2, sx[j]); xmx2 = fmaxf(xmx2, sx[j]);
          ymn2 = fminf(ymn2, sy[j]); ymx2 = fmaxf(ymx2, sy[j]);
        }
#pragma unroll
        for (int m = 32; m >= 1; m >>= 1) {
          xmn2 = fminf(xmn2, __shfl_xor(xmn2, m, 64));
          xmx2 = fmaxf(xmx2, __shfl_xor(xmx2, m, 64));
          ymn2 = fminf(ymn2, __shfl_xor(ymn2, m, 64));
          ymx2 = fmaxf(ymx2, __shfl_xor(ymx2, m, 64));
        }
        float xminp2 = xmn2 * 10.5f, xmaxp2 = xmx2 * 10.5f;
        float yminp2 = ymn2 * 10.5f, ymaxp2 = ymx2 * 10.5f;
        float bxf2 = floorf(xminp2), byf2 = floorf(yminp2);
        bool fast2 = (bxf2 >= 0.0f) && (byf2 >= 0.0f) &&
                     (bxf2 <= 488.0f) && (byf2 <= 488.0f) &&
                     (xmaxp2 < bxf2 + 23.0f) && (ymaxp2 < byf2 + 23.0f);
        if (fast2) {
          int bx2 = (int)bxf2, by2 = (int)byf2;
          int gbase2 = by2 * 512 + bx2;
          int cb2 = by2 * RSTR + bx2;
#pragma unroll
          for (int i = 0; i < 9; i++) S.regB[loff[i]] = F1[gbase2 + soff[i]];
          __syncthreads();
#pragma unroll
          for (int j = 0; j < NPT; j++) {
            float x = sx[j] * 10.5f, y = sy[j] * 10.5f;
            float w[4]; int id;
            wcalc(x, y, cb2, w, &id);
            scv[j] = rsum(S.regB, w, id);
          }
        } else {
#pragma unroll
          for (int j = 0; j < NPT; j++) {
            float x = sx[j] * 10.5f, y = sy[j] * 10.5f;
            scv[j] = bilinf(F1, x, y);
          }
        }
#pragma unroll
        for (int j = 0; j < NPT; j++) {
          if (act) {
            int k = lane * NPT + j;
            float d2 = fv[j] - scv[j];
            float bw = d2 * wwv[j];
            float u0 = ixv[j] * bw;
            float u1 = iyv[j] * bw;
            S.pqT[4][k] = u0;
            S.pqT[5][k] = u1;
          }
        }
        __syncthreads();
        // ATb: 2 chains in 2x32-lane groups, b128 reads, ascending-k adds.
        float accB = 0.f;
#pragma unroll 11
        for (int m = 0; m < 110; m++) {
          float4 v = *reinterpret_cast<const float4*>(&rowB[4 * m]);
          accB = accB + v.x;
          accB = accB + v.y;
          accB = accB + v.z;
          accB = accB + v.w;
        }
        accB = accB + rowB[440];
        s0 = __shfl(accB, 0,  64);
        s1 = __shfl(accB, 32, 64);
      }
      float e0 = dN * s0;
      float e1 = bb * s1;
      float numx = e0 - e1;
      float vx = inv_det * numx;
      float f0 = (-cN) * s0;
      float f1 = aa * s1;
      float numy = f0 + f1;
      float vy = inv_det * numy;
#pragma unroll
      for (int j = 0; j < NPT; j++) { sx[j] = sx[j] + vx; sy[j] = sy[j] + vy; }
      if (it == 0) { svx = vx;       svy = vy; }
      else         { svx = svx + vx; svy = svy + vy; }
      __syncthreads();                   // pqT/reg reads done before rewrite
    }

    px = px + svx; py = py + svy;        // pos = prev + sum_v (f32)
    if (lane == 0) {
      float* o = out + ((size_t)tr * SS + (t + 1)) * 2;
      float n0 = px - CRF; o[0] = n0 / CRF;
      float n1 = py - CRF; o[1] = n1 / CRF;
    }
  }
}

extern "C" void kernel_launch(void* const* d_in, const int* in_sizes, int n_in,
                              void* d_out, int out_size, void* d_ws, size_t ws_size,
                              hipStream_t stream) {
  const float* tl   = (const float*)d_in[0];  // (8,256,2) f32
  const float* imgs = (const float*)d_in[1];  // (8,16,512,512,1) f32
  float* o          = (float*)d_out;          // 65536 f32
  lk_track<<<dim3(2048), dim3(64), 0, stream>>>(tl, imgs, o);
}